// Round 1
// baseline (164.812 us; speedup 1.0000x reference)
//
#include <hip/hip_runtime.h>
#include <math.h>

#define FEAT 512

// Output layout (float32), flat concat in return order:
//   A_real [1024,256,256] @ 0
//   A_imag [1024,256,256] @ 67108864
//   D_real [1024,16,16]   @ 134217728
//   D_imag [1024,16,16]   @ 134479872
//   C      [256,16]       @ 134742016
#define A_IMAG_OFF 67108864
#define DR_OFF     134217728
#define DI_OFF     134479872
#define C_OFF      134742016
#define NFILL4     16777216   // float4 count per A matrix (1024*256*64)

// GEMM: Y[b][n] = x[b,:] . W[n,:] + bias[n]  for n in [0,768)
// n<256 -> theta (sincos -> A diagonals); 256..511 -> Dr raw; 512..767 -> Di raw
__global__ __launch_bounds__(256) void gemm_kernel(
    const float* __restrict__ x,
    const float* __restrict__ Wt, const float* __restrict__ bt,
    const float* __restrict__ Wr, const float* __restrict__ br,
    const float* __restrict__ Wi, const float* __restrict__ bi,
    float* __restrict__ out)
{
    __shared__ float XsT[32][64];   // [f_local][batch_row]  (transposed)
    __shared__ float WsT[32][64];   // [f_local][out_row]
    const int b0  = blockIdx.x * 64;       // batch tile (16 tiles)
    const int n0g = blockIdx.y * 64;       // output tile (12 tiles over 768)
    const int mat = n0g >> 8;              // 0=theta 1=Dr 2=Di (64 divides 256)
    const int n0  = n0g & 255;
    const float* __restrict__ W    = (mat == 0) ? Wt : (mat == 1) ? Wr : Wi;
    const float* __restrict__ bias = (mat == 0) ? bt : (mat == 1) ? br : bi;
    const int t  = threadIdx.x;
    const int tx = t & 15, ty = t >> 4;

    float acc[4][4] = {{0.f, 0.f, 0.f, 0.f}, {0.f, 0.f, 0.f, 0.f},
                       {0.f, 0.f, 0.f, 0.f}, {0.f, 0.f, 0.f, 0.f}};

    for (int f0 = 0; f0 < FEAT; f0 += 32) {
        #pragma unroll
        for (int l = 0; l < 2; ++l) {
            int q   = t + l * 256;         // 0..511 : 64 rows x 8 float4
            int row = q >> 3, c4 = q & 7;
            float4 v = *(const float4*)(x + (b0 + row) * FEAT + f0 + c4 * 4);
            XsT[c4 * 4 + 0][row] = v.x; XsT[c4 * 4 + 1][row] = v.y;
            XsT[c4 * 4 + 2][row] = v.z; XsT[c4 * 4 + 3][row] = v.w;
            float4 w = *(const float4*)(W + (n0 + row) * FEAT + f0 + c4 * 4);
            WsT[c4 * 4 + 0][row] = w.x; WsT[c4 * 4 + 1][row] = w.y;
            WsT[c4 * 4 + 2][row] = w.z; WsT[c4 * 4 + 3][row] = w.w;
        }
        __syncthreads();
        #pragma unroll
        for (int kk = 0; kk < 32; ++kk) {
            float4 a4 = *(const float4*)&XsT[kk][ty * 4];
            float4 w4 = *(const float4*)&WsT[kk][tx * 4];
            float a[4] = {a4.x, a4.y, a4.z, a4.w};
            float w[4] = {w4.x, w4.y, w4.z, w4.w};
            #pragma unroll
            for (int i = 0; i < 4; ++i)
                #pragma unroll
                for (int j = 0; j < 4; ++j)
                    acc[i][j] = fmaf(a[i], w[j], acc[i][j]);
        }
        __syncthreads();
    }

    #pragma unroll
    for (int i = 0; i < 4; ++i) {
        int b = b0 + ty * 4 + i;
        #pragma unroll
        for (int j = 0; j < 4; ++j) {
            int nl  = n0 + tx * 4 + j;
            float y = acc[i][j] + bias[nl];
            if (mat == 0) {
                float s, c;
                sincosf(y, &s, &c);
                out[b * 65536 + nl * 257] = c;               // A_real diag
                out[A_IMAG_OFF + b * 65536 + nl * 257] = s;  // A_imag diag
            } else if (mat == 1) {
                out[DR_OFF + b * 256 + nl] = y;              // raw Dr
            } else {
                out[DI_OFF + b * 256 + nl] = y;              // raw Di
            }
        }
    }
}

// Per-batch: norm = 4*sqrt(sum(Dr^2+Di^2)); scale Dr/Di in place by sqrt(10)/norm.
__global__ __launch_bounds__(256) void normscale_kernel(float* __restrict__ out)
{
    const int b = blockIdx.x;
    const int t = threadIdx.x;
    float dr = out[DR_OFF + b * 256 + t];
    float di = out[DI_OFF + b * 256 + t];
    float s  = dr * dr + di * di;
    #pragma unroll
    for (int o = 32; o > 0; o >>= 1) s += __shfl_down(s, o);
    __shared__ float red[4];
    if ((t & 63) == 0) red[t >> 6] = s;
    __syncthreads();
    float sum   = red[0] + red[1] + red[2] + red[3];
    float scale = 3.16227766016838f / (4.f * sqrtf(sum));  // sqrt(10)/norm
    out[DR_OFF + b * 256 + t] = dr * scale;
    out[DI_OFF + b * 256 + t] = di * scale;
}

// Stream float4 zeros into A_real+A_imag (skipping the diagonal float which
// gemm_kernel wrote), and copy C through.
__global__ __launch_bounds__(256) void fill_kernel(float* __restrict__ out,
                                                   const float* __restrict__ Cin)
{
    int t = blockIdx.x * 256 + threadIdx.x;
    if (t < NFILL4) {
        int c4 = t & 63;           // float4 index within row
        int m  = (t >> 6) & 255;   // row within matrix
        float* pr = out + 4 * t;
        float* pi = out + A_IMAG_OFF + 4 * t;
        if (c4 != (m >> 2)) {
            float4 z = make_float4(0.f, 0.f, 0.f, 0.f);
            *(float4*)pr = z;
            *(float4*)pi = z;
        } else {
            int d = m & 3;         // diagonal component — don't touch it
            #pragma unroll
            for (int j = 0; j < 4; ++j)
                if (j != d) { pr[j] = 0.f; pi[j] = 0.f; }
        }
    } else {
        int q = t - NFILL4;        // 0..1023 : C is 4096 floats = 1024 float4
        float4 v = *(const float4*)(Cin + 4 * q);
        *(float4*)(out + C_OFF + 4 * q) = v;
    }
}

extern "C" void kernel_launch(void* const* d_in, const int* in_sizes, int n_in,
                              void* d_out, int out_size, void* d_ws, size_t ws_size,
                              hipStream_t stream)
{
    const float* x  = (const float*)d_in[0];
    const float* Wt = (const float*)d_in[1];
    const float* bt = (const float*)d_in[2];
    const float* Wr = (const float*)d_in[3];
    const float* br = (const float*)d_in[4];
    const float* Wi = (const float*)d_in[5];
    const float* bi = (const float*)d_in[6];
    const float* C  = (const float*)d_in[7];
    float* out = (float*)d_out;

    dim3 g1(16, 12);
    gemm_kernel<<<g1, 256, 0, stream>>>(x, Wt, bt, Wr, br, Wi, bi, out);
    normscale_kernel<<<1024, 256, 0, stream>>>(out);
    fill_kernel<<<(NFILL4 + 1024) / 256, 256, 0, stream>>>(out, C);
}

// Round 2
// 157.230 us; speedup vs baseline: 1.0482x; 1.0482x over previous
//
#include <hip/hip_runtime.h>
#include <math.h>

#define FEAT 512

// Output layout (float32), flat concat:
//   A_real [1024,256,256] @ 0
//   A_imag [1024,256,256] @ 67108864
//   D_real [1024,16,16]   @ 134217728
//   D_imag [1024,16,16]   @ 134479872
//   C      [256,16]       @ 134742016
#define A_IMAG_OFF 67108864
#define DR_OFF     134217728
#define DI_OFF     134479872
#define C_OFF      134742016
#define NFILL4     16777216   // float4 count per A matrix (1024*256*64)
#define ND4       65536       // float4 count of one D matrix (1024*256/4)

typedef __attribute__((ext_vector_type(8))) short bf16x8;
typedef __attribute__((ext_vector_type(4))) float f32x4;

// round-to-nearest-even fp32 -> bf16 bits
__device__ inline short bf16_rne(float f) {
    unsigned u = __float_as_uint(f);
    unsigned r = (u + 0x7FFFu + ((u >> 16) & 1u)) >> 16;
    return (short)r;
}

// split f into hi (bf16) + lo (bf16 of remainder)
__device__ inline void split8(const float* f, bf16x8& hi, bf16x8& lo) {
    #pragma unroll
    for (int j = 0; j < 8; ++j) {
        short h = bf16_rne(f[j]);
        hi[j] = h;
        float hf = __uint_as_float(((unsigned)(unsigned short)h) << 16);
        lo[j] = bf16_rne(f[j] - hf);
    }
}

// GEMM Y[b][c] = x[b,:].W[c,:] + bias  over c in [0,768) via split-bf16 MFMA.
// c<256: theta -> sincos -> A diagonals.  256..511: raw Dr.  512..767: raw Di.
// Dr/Di blocks also accumulate per-batch sum(y^2) into wsn via atomics.
__global__ __launch_bounds__(256) void gemm_mfma_kernel(
    const float* __restrict__ x,
    const float* __restrict__ Wt, const float* __restrict__ bt,
    const float* __restrict__ Wr, const float* __restrict__ br,
    const float* __restrict__ Wi, const float* __restrict__ bi,
    float* __restrict__ out, float* __restrict__ wsn)
{
    const int b0  = blockIdx.x * 64;
    const int n0g = blockIdx.y * 64;
    const int mat = n0g >> 8;              // 0=theta 1=Dr 2=Di
    const int n0  = n0g & 255;
    const float* __restrict__ W    = (mat == 0) ? Wt : (mat == 1) ? Wr : Wi;
    const float* __restrict__ bias = (mat == 0) ? bt : (mat == 1) ? br : bi;

    const int t  = threadIdx.x;
    const int l  = t & 63;
    const int w  = t >> 6;                 // wave id 0..3
    const int wr = w >> 1, wc = w & 1;     // 2x2 wave grid (32x32 each)
    const int lr = l & 15;                 // A-row / B-col / D-col within frag
    const int kg = l >> 4;                 // k-group (8 consecutive k)

    const int arow0 = b0 + wr * 32 + lr;   // + mi*16
    const int bcol0 = n0 + wc * 32 + lr;   // + ni*16

    f32x4 acc[2][2] = {};

    for (int f0 = 0; f0 < FEAT; f0 += 32) {
        const int ks = f0 + kg * 8;
        bf16x8 ah[2], al[2], bh[2], bl[2];
        #pragma unroll
        for (int mi = 0; mi < 2; ++mi) {
            const float* p = x + (size_t)(arow0 + mi * 16) * FEAT + ks;
            float4 v0 = *(const float4*)p, v1 = *(const float4*)(p + 4);
            float f[8] = {v0.x, v0.y, v0.z, v0.w, v1.x, v1.y, v1.z, v1.w};
            split8(f, ah[mi], al[mi]);
        }
        #pragma unroll
        for (int ni = 0; ni < 2; ++ni) {
            const float* p = W + (size_t)(bcol0 + ni * 16) * FEAT + ks;
            float4 v0 = *(const float4*)p, v1 = *(const float4*)(p + 4);
            float f[8] = {v0.x, v0.y, v0.z, v0.w, v1.x, v1.y, v1.z, v1.w};
            split8(f, bh[ni], bl[ni]);
        }
        #pragma unroll
        for (int mi = 0; mi < 2; ++mi)
            #pragma unroll
            for (int ni = 0; ni < 2; ++ni) {
                acc[mi][ni] = __builtin_amdgcn_mfma_f32_16x16x32_bf16(ah[mi], bh[ni], acc[mi][ni], 0, 0, 0);
                acc[mi][ni] = __builtin_amdgcn_mfma_f32_16x16x32_bf16(ah[mi], bl[ni], acc[mi][ni], 0, 0, 0);
                acc[mi][ni] = __builtin_amdgcn_mfma_f32_16x16x32_bf16(al[mi], bh[ni], acc[mi][ni], 0, 0, 0);
            }
    }

    // y values: D row = kg*4 + r (batch), D col = lr (+ni*16) (output col)
    float y[2][2][4];
    #pragma unroll
    for (int mi = 0; mi < 2; ++mi)
        #pragma unroll
        for (int ni = 0; ni < 2; ++ni) {
            float bv = bias[bcol0 + ni * 16];
            #pragma unroll
            for (int r = 0; r < 4; ++r)
                y[mi][ni][r] = acc[mi][ni][r] + bv;
        }

    if (mat == 0) {
        #pragma unroll
        for (int mi = 0; mi < 2; ++mi)
            #pragma unroll
            for (int ni = 0; ni < 2; ++ni)
                #pragma unroll
                for (int r = 0; r < 4; ++r) {
                    int b = b0 + wr * 32 + mi * 16 + kg * 4 + r;
                    int m = bcol0 + ni * 16;
                    float s, c;
                    sincosf(y[mi][ni][r], &s, &c);
                    out[(size_t)b * 65536 + m * 257] = c;               // A_real diag
                    out[A_IMAG_OFF + (size_t)b * 65536 + m * 257] = s;  // A_imag diag
                }
    } else {
        const size_t base = (mat == 1) ? DR_OFF : DI_OFF;
        #pragma unroll
        for (int mi = 0; mi < 2; ++mi)
            #pragma unroll
            for (int ni = 0; ni < 2; ++ni)
                #pragma unroll
                for (int r = 0; r < 4; ++r) {
                    int b = b0 + wr * 32 + mi * 16 + kg * 4 + r;
                    out[base + (size_t)b * 256 + bcol0 + ni * 16] = y[mi][ni][r];
                }
        // per-batch partial sum of y^2 (both ni), reduced over the 16 cols
        #pragma unroll
        for (int mi = 0; mi < 2; ++mi)
            #pragma unroll
            for (int r = 0; r < 4; ++r) {
                float v = y[mi][0][r] * y[mi][0][r] + y[mi][1][r] * y[mi][1][r];
                v += __shfl_xor(v, 1);
                v += __shfl_xor(v, 2);
                v += __shfl_xor(v, 4);
                v += __shfl_xor(v, 8);
                if (lr == 0)
                    atomicAdd(&wsn[b0 + wr * 32 + mi * 16 + kg * 4 + r], v);
            }
    }
}

// Fill A off-diagonals with zeros (diagonal floats written by gemm kernel),
// scale Dr/Di in place by sqrt(10)/(4*sqrt(wsn[b])), copy C.
__global__ __launch_bounds__(256) void fill_scale_kernel(
    float* __restrict__ out, const float* __restrict__ Cin,
    const float* __restrict__ wsn)
{
    int t = blockIdx.x * 256 + threadIdx.x;
    if (t < NFILL4) {
        int c4 = t & 63;           // float4 index within row
        int m  = (t >> 6) & 255;   // row within matrix
        float* pr = out + 4 * (size_t)t;
        float* pi = out + A_IMAG_OFF + 4 * (size_t)t;
        if (c4 != (m >> 2)) {
            float4 z = make_float4(0.f, 0.f, 0.f, 0.f);
            *(float4*)pr = z;
            *(float4*)pi = z;
        } else {
            int d = m & 3;         // diagonal element — don't touch it
            #pragma unroll
            for (int j = 0; j < 4; ++j)
                if (j != d) { pr[j] = 0.f; pi[j] = 0.f; }
        }
    } else if (t < NFILL4 + 2 * ND4) {
        int q = t - NFILL4;                      // 0..131071 over Dr||Di
        int qq = q & (ND4 - 1);
        int b  = qq >> 6;                        // 64 float4 per batch
        float scale = 0.7905694150420949f * rsqrtf(wsn[b]);  // sqrt(10)/4/sqrt(sum)
        float* p = out + ((q < ND4) ? DR_OFF : DI_OFF) + 4 * (size_t)qq;
        float4 v = *(float4*)p;
        v.x *= scale; v.y *= scale; v.z *= scale; v.w *= scale;
        *(float4*)p = v;
    } else {
        int q = t - NFILL4 - 2 * ND4;            // 0..1023 : C = 1024 float4
        *(float4*)(out + C_OFF + 4 * q) = *(const float4*)(Cin + 4 * q);
    }
}

extern "C" void kernel_launch(void* const* d_in, const int* in_sizes, int n_in,
                              void* d_out, int out_size, void* d_ws, size_t ws_size,
                              hipStream_t stream)
{
    const float* x  = (const float*)d_in[0];
    const float* Wt = (const float*)d_in[1];
    const float* bt = (const float*)d_in[2];
    const float* Wr = (const float*)d_in[3];
    const float* br = (const float*)d_in[4];
    const float* Wi = (const float*)d_in[5];
    const float* bi = (const float*)d_in[6];
    const float* C  = (const float*)d_in[7];
    float* out = (float*)d_out;
    float* wsn = (float*)d_ws;   // 1024 floats: per-batch sum(Dr^2+Di^2)

    hipMemsetAsync(wsn, 0, 1024 * sizeof(float), stream);

    dim3 g1(16, 12);
    gemm_mfma_kernel<<<g1, 256, 0, stream>>>(x, Wt, bt, Wr, br, Wi, bi, out, wsn);

    int nblk = (NFILL4 + 2 * ND4 + 1024 + 255) / 256;
    fill_scale_kernel<<<nblk, 256, 0, stream>>>(out, C, wsn);
}

// Round 3
// 143.989 us; speedup vs baseline: 1.1446x; 1.0920x over previous
//
#include <hip/hip_runtime.h>
#include <math.h>

#define FEAT 512

// Output layout (float32), flat concat:
//   A_real [1024,256,256] @ 0
//   A_imag [1024,256,256] @ 67108864
//   D_real [1024,16,16]   @ 134217728
//   D_imag [1024,16,16]   @ 134479872
//   C      [256,16]       @ 134742016
#define A_IMAG_OFF 67108864
#define DR_OFF     134217728
#define DI_OFF     134479872
#define C_OFF      134742016
#define NFILL4     16777216   // float4 count per A matrix (1024*256*64)
#define ND4        65536      // float4 count of one D matrix
#define GEMM_BLOCKS 192       // 16 batch-tiles x 12 col-tiles

typedef __attribute__((ext_vector_type(8))) short bf16x8;
typedef __attribute__((ext_vector_type(4))) float f32x4;

// round-to-nearest-even fp32 -> bf16 bits
__device__ inline short bf16_rne(float f) {
    unsigned u = __float_as_uint(f);
    unsigned r = (u + 0x7FFFu + ((u >> 16) & 1u)) >> 16;
    return (short)r;
}

// split f into hi (bf16) + lo (bf16 of remainder)
__device__ inline void split8(const float* f, bf16x8& hi, bf16x8& lo) {
    #pragma unroll
    for (int j = 0; j < 8; ++j) {
        short h = bf16_rne(f[j]);
        hi[j] = h;
        float hf = __uint_as_float(((unsigned)(unsigned short)h) << 16);
        lo[j] = bf16_rne(f[j] - hf);
    }
}

// Fused: blocks [0,192) do the 1024x768x512 GEMM (theta->sincos diag, raw Dr/Di,
// norm atomics); remaining blocks stream A off-diagonal zeros + copy C.
// GEMM and fill touch float-disjoint addresses -> safe in one launch.
__global__ __launch_bounds__(256) void fused_kernel(
    const float* __restrict__ x,
    const float* __restrict__ Wt, const float* __restrict__ bt,
    const float* __restrict__ Wr, const float* __restrict__ br,
    const float* __restrict__ Wi, const float* __restrict__ bi,
    const float* __restrict__ Cin,
    float* __restrict__ out, float* __restrict__ wsn)
{
    const int bid = blockIdx.x;

    if (bid >= GEMM_BLOCKS) {
        // ---------------- fill path: A off-diagonals + C ----------------
        int t = (bid - GEMM_BLOCKS) * 256 + threadIdx.x;   // [0, NFILL4+1024)
        if (t < NFILL4) {
            int c4 = t & 63;           // float4 index within row
            int m  = (t >> 6) & 255;   // row within matrix
            float* pr = out + 4 * (size_t)t;
            float* pi = out + A_IMAG_OFF + 4 * (size_t)t;
            if (c4 != (m >> 2)) {
                float4 z = make_float4(0.f, 0.f, 0.f, 0.f);
                *(float4*)pr = z;
                *(float4*)pi = z;
            } else {
                int d = m & 3;         // diagonal element — GEMM writes it
                #pragma unroll
                for (int j = 0; j < 4; ++j)
                    if (j != d) { pr[j] = 0.f; pi[j] = 0.f; }
            }
        } else {
            int q = t - NFILL4;        // 0..1023 : C = 1024 float4
            *(float4*)(out + C_OFF + 4 * q) = *(const float4*)(Cin + 4 * q);
        }
        return;
    }

    // ---------------- GEMM path ----------------
    const int b0  = (bid & 15) * 64;       // batch tile
    const int n0g = (bid >> 4) * 64;       // output-col tile over 768
    const int mat = n0g >> 8;              // 0=theta 1=Dr 2=Di
    const int n0  = n0g & 255;
    const float* __restrict__ W    = (mat == 0) ? Wt : (mat == 1) ? Wr : Wi;
    const float* __restrict__ bias = (mat == 0) ? bt : (mat == 1) ? br : bi;

    const int t  = threadIdx.x;
    const int l  = t & 63;
    const int w  = t >> 6;                 // wave id 0..3
    const int wr = w >> 1, wc = w & 1;     // 2x2 wave grid (32x32 each)
    const int lr = l & 15;
    const int kg = l >> 4;                 // k-group (8 consecutive k)

    const int arow0 = b0 + wr * 32 + lr;
    const int bcol0 = n0 + wc * 32 + lr;

    f32x4 acc[2][2] = {};

    for (int f0 = 0; f0 < FEAT; f0 += 32) {
        const int ks = f0 + kg * 8;
        bf16x8 ah[2], al[2], bh[2], bl[2];
        #pragma unroll
        for (int mi = 0; mi < 2; ++mi) {
            const float* p = x + (size_t)(arow0 + mi * 16) * FEAT + ks;
            float4 v0 = *(const float4*)p, v1 = *(const float4*)(p + 4);
            float f[8] = {v0.x, v0.y, v0.z, v0.w, v1.x, v1.y, v1.z, v1.w};
            split8(f, ah[mi], al[mi]);
        }
        #pragma unroll
        for (int ni = 0; ni < 2; ++ni) {
            const float* p = W + (size_t)(bcol0 + ni * 16) * FEAT + ks;
            float4 v0 = *(const float4*)p, v1 = *(const float4*)(p + 4);
            float f[8] = {v0.x, v0.y, v0.z, v0.w, v1.x, v1.y, v1.z, v1.w};
            split8(f, bh[ni], bl[ni]);
        }
        #pragma unroll
        for (int mi = 0; mi < 2; ++mi)
            #pragma unroll
            for (int ni = 0; ni < 2; ++ni) {
                acc[mi][ni] = __builtin_amdgcn_mfma_f32_16x16x32_bf16(ah[mi], bh[ni], acc[mi][ni], 0, 0, 0);
                acc[mi][ni] = __builtin_amdgcn_mfma_f32_16x16x32_bf16(ah[mi], bl[ni], acc[mi][ni], 0, 0, 0);
                acc[mi][ni] = __builtin_amdgcn_mfma_f32_16x16x32_bf16(al[mi], bh[ni], acc[mi][ni], 0, 0, 0);
            }
    }

    float y[2][2][4];
    #pragma unroll
    for (int mi = 0; mi < 2; ++mi)
        #pragma unroll
        for (int ni = 0; ni < 2; ++ni) {
            float bv = bias[bcol0 + ni * 16];
            #pragma unroll
            for (int r = 0; r < 4; ++r)
                y[mi][ni][r] = acc[mi][ni][r] + bv;
        }

    if (mat == 0) {
        #pragma unroll
        for (int mi = 0; mi < 2; ++mi)
            #pragma unroll
            for (int ni = 0; ni < 2; ++ni)
                #pragma unroll
                for (int r = 0; r < 4; ++r) {
                    int b = b0 + wr * 32 + mi * 16 + kg * 4 + r;
                    int m = bcol0 + ni * 16;
                    float s, c;
                    sincosf(y[mi][ni][r], &s, &c);
                    out[(size_t)b * 65536 + m * 257] = c;               // A_real diag
                    out[A_IMAG_OFF + (size_t)b * 65536 + m * 257] = s;  // A_imag diag
                }
    } else {
        const size_t base = (mat == 1) ? DR_OFF : DI_OFF;
        #pragma unroll
        for (int mi = 0; mi < 2; ++mi)
            #pragma unroll
            for (int ni = 0; ni < 2; ++ni)
                #pragma unroll
                for (int r = 0; r < 4; ++r) {
                    int b = b0 + wr * 32 + mi * 16 + kg * 4 + r;
                    out[base + (size_t)b * 256 + bcol0 + ni * 16] = y[mi][ni][r];
                }
        #pragma unroll
        for (int mi = 0; mi < 2; ++mi)
            #pragma unroll
            for (int r = 0; r < 4; ++r) {
                float v = y[mi][0][r] * y[mi][0][r] + y[mi][1][r] * y[mi][1][r];
                v += __shfl_xor(v, 1);
                v += __shfl_xor(v, 2);
                v += __shfl_xor(v, 4);
                v += __shfl_xor(v, 8);
                if (lr == 0)
                    atomicAdd(&wsn[b0 + wr * 32 + mi * 16 + kg * 4 + r], v);
            }
    }
}

// Scale Dr/Di in place by sqrt(10)/(4*sqrt(wsn[b])).
__global__ __launch_bounds__(256) void scale_kernel(
    float* __restrict__ out, const float* __restrict__ wsn)
{
    int q  = blockIdx.x * 256 + threadIdx.x;     // [0, 2*ND4)
    int qq = q & (ND4 - 1);
    int b  = qq >> 6;                            // 64 float4 per batch
    float scale = 0.7905694150420949f * rsqrtf(wsn[b]);  // sqrt(10)/4/sqrt(sum)
    float* p = out + ((q < ND4) ? DR_OFF : DI_OFF) + 4 * (size_t)qq;
    float4 v = *(float4*)p;
    v.x *= scale; v.y *= scale; v.z *= scale; v.w *= scale;
    *(float4*)p = v;
}

extern "C" void kernel_launch(void* const* d_in, const int* in_sizes, int n_in,
                              void* d_out, int out_size, void* d_ws, size_t ws_size,
                              hipStream_t stream)
{
    const float* x  = (const float*)d_in[0];
    const float* Wt = (const float*)d_in[1];
    const float* bt = (const float*)d_in[2];
    const float* Wr = (const float*)d_in[3];
    const float* br = (const float*)d_in[4];
    const float* Wi = (const float*)d_in[5];
    const float* bi = (const float*)d_in[6];
    const float* C  = (const float*)d_in[7];
    float* out = (float*)d_out;
    float* wsn = (float*)d_ws;   // 1024 floats: per-batch sum(Dr^2+Di^2)

    hipMemsetAsync(wsn, 0, 1024 * sizeof(float), stream);

    // 192 GEMM blocks + 65536 A-fill blocks + 4 C-copy blocks
    int nblk = GEMM_BLOCKS + (NFILL4 + 1024) / 256;
    fused_kernel<<<nblk, 256, 0, stream>>>(x, Wt, bt, Wr, br, Wi, bi, C, out, wsn);

    scale_kernel<<<2 * ND4 / 256, 256, 0, stream>>>(out, wsn);
}